// Round 9
// baseline (959.678 us; speedup 1.0000x reference)
//
#include <hip/hip_runtime.h>
#include <math.h>

#define NTOK 320
#define BB   64
#define RTOT (BB * NTOK)   // 20480 token rows
#define DIMC 512
#define HIDC 256
#define NHEAD 8

typedef unsigned short u16;
typedef __attribute__((ext_vector_type(8))) short bf8_t;           // 8 bf16
typedef __attribute__((ext_vector_type(4))) float f4_t;
typedef __attribute__((ext_vector_type(4))) unsigned short us4_t;

#define F_BIAS  1
#define F_RELU  2
#define F_F32   4
#define F_PACK  8
#define F_RES1P 16
#define F_RES2P 32
#define F_RESX1 64

__device__ __forceinline__ void bsplit(float f, u16& h, u16& l) {
    const unsigned u = __float_as_uint(f);
    h = (u16)(u >> 16);
    const float fl = f - __uint_as_float(u & 0xffff0000u);
    l = (u16)(__float_as_uint(fl) >> 16);
}
__device__ __forceinline__ float brecon(u16 h, u16 l) {
    return __uint_as_float((unsigned)h << 16) + __uint_as_float((unsigned)l << 16);
}

// ---- pack all weights into bf16 hi/lo planes, orientation [out_j][d] ----
// offsets (elements): WL=0[1024][512] WD=524288[256][512] WU=655360[512][256]
// WE=786432[512][512] WQ=1048576[256][256] WKV=1114112[512][256] WO=1245184[256][256]
__global__ __launch_bounds__(256)
void pack_w_k(const float* __restrict__ Wlin, const float* __restrict__ Wdown,
              const float* __restrict__ Wup,  const float* __restrict__ Wend,
              const float* __restrict__ Wq,   const float* __restrict__ Wk,
              const float* __restrict__ Wv,   const float* __restrict__ Wo,
              u16* __restrict__ Ph, u16* __restrict__ Pl)
{
    const int idx = blockIdx.x * 256 + threadIdx.x;
    if (idx >= 1310720) return;
    float v;
    int i = idx;
    if      (i < 524288) { const int j = i >> 9, d = i & 511; v = Wlin[d * 1024 + j]; }
    else if (i < 655360) { i -= 524288; const int j = i >> 9, d = i & 511; v = Wdown[d * 256 + j]; }
    else if (i < 786432) { i -= 655360; const int j = i >> 8, d = i & 255; v = Wup[d * 512 + j]; }
    else if (i < 1048576){ i -= 786432; const int j = i >> 9, d = i & 511; v = Wend[d * 512 + j]; }
    else if (i < 1114112){ v = Wq[i - 1048576]; }
    else if (i < 1245184){ i -= 1114112; v = (i < 65536) ? Wk[i] : Wv[i - 65536]; }
    else                 { v = Wo[i - 1245184]; }
    u16 h, l; bsplit(v, h, l);
    Ph[idx] = h; Pl[idx] = l;
}

// ---- transpose x (B,512,320) channel-major -> token-major packed planes ----
__global__ __launch_bounds__(256)
void pack_x_k(const float* __restrict__ x1, const float* __restrict__ x2,
              u16* __restrict__ X1h, u16* __restrict__ X1l,
              u16* __restrict__ X2h, u16* __restrict__ X2l)
{
    __shared__ float tile[64 * 65];
    const int b = blockIdx.z & 63, which = blockIdx.z >> 6;
    const float* src = which ? x2 : x1;
    u16* Dh = which ? X2h : X1h;
    u16* Dl = which ? X2l : X1l;
    const int c0 = blockIdx.x << 6, n0 = blockIdx.y << 6;
    const int t = threadIdx.x, col = t & 63, rq = t >> 6;
    const float* sb_ = src + (long)b * DIMC * NTOK;
    #pragma unroll
    for (int i = 0; i < 16; ++i) {
        const int c = rq * 16 + i;
        tile[c * 65 + col] = sb_[(long)(c0 + c) * NTOK + n0 + col];
    }
    __syncthreads();
    #pragma unroll
    for (int i = 0; i < 16; ++i) {
        const int nr = rq * 16 + i;
        u16 h, l; bsplit(tile[col * 65 + nr], h, l);
        const long o = (long)(b * NTOK + n0 + nr) * DIMC + c0 + col;
        Dh[o] = h; Dl[o] = l;
    }
}

// ---- LDS-free token-major bf16x3 MFMA GEMM ----
// C[r][j] = epi( sum_d B[r][d] * A[j][d] );  A,B packed bf16 hi/lo planes,
// both K-contiguous.  Fragments loaded DIRECTLY from global (L2-resident):
// no LDS, no barriers, no bank conflicts.  Block 128(j) x 128(r), 4 waves
// 2x2, wave tile 64x64 (4x4 16x16x32 frags, 48 MFMA per 16 loads).
template<int FLAGS, int DK, int JB>
__global__ __launch_bounds__(256)
void gemm_tm(const u16* __restrict__ Agh, const u16* __restrict__ Agl,
             const u16* __restrict__ Bgh, const u16* __restrict__ Bgl,
             float* __restrict__ Cf, int ldcf,
             u16* __restrict__ Ch, u16* __restrict__ Cl, int ldcp,
             const float* __restrict__ bias,
             const u16* __restrict__ R1h, const u16* __restrict__ R1l, int ldr1,
             const u16* __restrict__ R2h, const u16* __restrict__ R2l, int ldr2,
             const float* __restrict__ xres)
{
    // XCD-chunked bijective swizzle (grid = JB*160, divisible by 8):
    // each XCD gets a contiguous nb-range with j fastest -> same-r j-blocks
    // share one XCD's L2 for the B panel.
    const int nwg = JB * 160;
    const int nb  = (blockIdx.x & 7) * (nwg >> 3) + (blockIdx.x >> 3);
    const int j0 = (nb % JB) * 128;
    const int r0 = (nb / JB) * 128;

    const int t = threadIdx.x, lane = t & 63, wave = t >> 6;
    const int wq = wave >> 1, wr = wave & 1;
    const int r16 = lane & 15, g = lane >> 4;

    // per-lane base element offsets (frag row stride folded as constants)
    const int aoff = (j0 + wq * 64 + r16) * DK + g * 8;
    const int boff = (r0 + wr * 64 + r16) * DK + g * 8;

    f4_t acc[4][4];
    #pragma unroll
    for (int i = 0; i < 4; ++i)
        #pragma unroll
        for (int j = 0; j < 4; ++j)
            acc[i][j] = (f4_t){0.f, 0.f, 0.f, 0.f};

    #pragma unroll 2
    for (int d0 = 0; d0 < DK; d0 += 32) {
        bf8_t ah[4], al[4], bh[4], bl[4];
        #pragma unroll
        for (int fm = 0; fm < 4; ++fm) {
            ah[fm] = *(const bf8_t*)&Agh[aoff + fm * 16 * DK + d0];
            al[fm] = *(const bf8_t*)&Agl[aoff + fm * 16 * DK + d0];
        }
        #pragma unroll
        for (int fn = 0; fn < 4; ++fn) {
            bh[fn] = *(const bf8_t*)&Bgh[boff + fn * 16 * DK + d0];
            bl[fn] = *(const bf8_t*)&Bgl[boff + fn * 16 * DK + d0];
        }
        #pragma unroll
        for (int fm = 0; fm < 4; ++fm)
            #pragma unroll
            for (int fn = 0; fn < 4; ++fn) {
                acc[fm][fn] = __builtin_amdgcn_mfma_f32_16x16x32_bf16(ah[fm], bh[fn], acc[fm][fn], 0, 0, 0);
                acc[fm][fn] = __builtin_amdgcn_mfma_f32_16x16x32_bf16(ah[fm], bl[fn], acc[fm][fn], 0, 0, 0);
                acc[fm][fn] = __builtin_amdgcn_mfma_f32_16x16x32_bf16(al[fm], bh[fn], acc[fm][fn], 0, 0, 0);
            }
    }

    // epilogue: frag D col = token (lane&15), rows = 4 consecutive j (g*4+reg)
    #pragma unroll
    for (int fm = 0; fm < 4; ++fm) {
        const int jb = j0 + wq * 64 + fm * 16 + g * 4;
        f4_t bv = (f4_t){0.f, 0.f, 0.f, 0.f};
        if (FLAGS & F_BIAS) bv = *(const f4_t*)&bias[jb];
        #pragma unroll
        for (int fn = 0; fn < 4; ++fn) {
            const int r = r0 + wr * 64 + fn * 16 + r16;
            f4_t v = acc[fm][fn];
            if (FLAGS & F_BIAS) v += bv;
            if (FLAGS & F_RES1P) {
                const us4_t rh = *(const us4_t*)&R1h[(long)r * ldr1 + jb];
                const us4_t rl = *(const us4_t*)&R1l[(long)r * ldr1 + jb];
                #pragma unroll
                for (int q = 0; q < 4; ++q) v[q] += brecon(rh[q], rl[q]);
            }
            if (FLAGS & F_RES2P) {
                const us4_t rh = *(const us4_t*)&R2h[(long)r * ldr2 + jb];
                const us4_t rl = *(const us4_t*)&R2l[(long)r * ldr2 + jb];
                #pragma unroll
                for (int q = 0; q < 4; ++q) v[q] += brecon(rh[q], rl[q]);
            }
            if (FLAGS & F_RESX1) {
                const unsigned rr = (unsigned)r;
                const int bb = rr / 320u;
                const int nn = rr - bb * 320u;
                #pragma unroll
                for (int q = 0; q < 4; ++q)
                    v[q] += xres[(long)bb * DIMC * NTOK + (long)(jb + q) * NTOK + nn];
            }
            if (FLAGS & F_RELU) {
                #pragma unroll
                for (int q = 0; q < 4; ++q) v[q] = fmaxf(v[q], 0.f);
            }
            if (FLAGS & F_F32)
                *(f4_t*)&Cf[(long)r * ldcf + jb] = v;
            if (FLAGS & F_PACK) {
                us4_t h4, l4;
                #pragma unroll
                for (int q = 0; q < 4; ++q) { u16 h, l; bsplit(v[q], h, l); h4[q] = h; l4[q] = l; }
                *(us4_t*)&Ch[(long)r * ldcp + jb] = h4;
                *(us4_t*)&Cl[(long)r * ldcp + jb] = l4;
            }
        }
    }
}

// ---- channel attention, token-major. grid (2 slices, 8 heads, 64 b). ----
// Q fp32 [r][256]; KV fp32 [r][512] (K cols 0..255, V cols 256..511).
// Q and K staged in LDS (pitch 34, ~74KB -> 2 blocks/CU); V streamed from L2.
__global__ __launch_bounds__(256)
void attn_tm(const float* __restrict__ Qf, const float* __restrict__ KVf,
             u16* __restrict__ AOh, u16* __restrict__ AOl,
             const float* __restrict__ temp)
{
    const int slice = blockIdx.x, h = blockIdx.y, b = blockIdx.z;
    const int rb = b * NTOK + (slice ? 64 : 0);
    const int Nt = slice ? 256 : 64;
    const int qc = h * 32;

    __shared__ float qs[256 * 34], ks[256 * 34];
    __shared__ float PT[32 * 36];                // P transposed: PT[d][c]
    __shared__ float invq[32], invk[32];
    const int t = threadIdx.x;

    for (int q = t; q < Nt * 8; q += 256) {      // stage Q,K (row=token, 32 ch)
        const int n = q >> 3, c4 = (q & 7) << 2;
        *(f4_t*)&qs[n * 34 + c4] = *(const f4_t*)&Qf[(long)(rb + n) * 256 + qc + c4];
        *(f4_t*)&ks[n * 34 + c4] = *(const f4_t*)&KVf[(long)(rb + n) * 512 + qc + c4];
    }
    __syncthreads();

    {   // l2 norms over tokens per channel
        const int c = t >> 3, l8 = t & 7;
        float sq = 0.f, sk = 0.f;
        for (int n = l8; n < Nt; n += 8) {
            const float qv = qs[n * 34 + c];
            sq = fmaf(qv, qv, sq);
            const float kv = ks[n * 34 + c];
            sk = fmaf(kv, kv, sk);
        }
        sq += __shfl_xor(sq, 1); sq += __shfl_xor(sq, 2); sq += __shfl_xor(sq, 4);
        sk += __shfl_xor(sk, 1); sk += __shfl_xor(sk, 2); sk += __shfl_xor(sk, 4);
        if (l8 == 0) {
            invq[c] = 1.f / fmaxf(sqrtf(sq), 1e-12f);
            invk[c] = 1.f / fmaxf(sqrtf(sk), 1e-12f);
        }
    }
    __syncthreads();

    {   // logits over d, softmax per row c  (all operands in LDS)
        const int c = t >> 3, db = (t & 7) << 2;
        float s0 = 0.f, s1 = 0.f, s2 = 0.f, s3 = 0.f;
        for (int n = 0; n < Nt; ++n) {
            const float qv = qs[n * 34 + c];
            const int o = n * 34 + db;
            s0 = fmaf(qv, ks[o + 0], s0);
            s1 = fmaf(qv, ks[o + 1], s1);
            s2 = fmaf(qv, ks[o + 2], s2);
            s3 = fmaf(qv, ks[o + 3], s3);
        }
        const float sc = invq[c] * temp[h];
        const float l0 = s0 * sc * invk[db + 0];
        const float l1 = s1 * sc * invk[db + 1];
        const float l2 = s2 * sc * invk[db + 2];
        const float l3 = s3 * sc * invk[db + 3];
        float m = fmaxf(fmaxf(l0, l1), fmaxf(l2, l3));
        m = fmaxf(m, __shfl_xor(m, 1));
        m = fmaxf(m, __shfl_xor(m, 2));
        m = fmaxf(m, __shfl_xor(m, 4));
        const float e0 = expf(l0 - m), e1 = expf(l1 - m);
        const float e2 = expf(l2 - m), e3 = expf(l3 - m);
        float s = e0 + e1 + e2 + e3;
        s += __shfl_xor(s, 1); s += __shfl_xor(s, 2); s += __shfl_xor(s, 4);
        const float inv = 1.f / s;
        PT[(db + 0) * 36 + c] = e0 * inv;
        PT[(db + 1) * 36 + c] = e1 * inv;
        PT[(db + 2) * 36 + c] = e2 * inv;
        PT[(db + 3) * 36 + c] = e3 * inv;
    }
    __syncthreads();

    for (int idx = t; idx < Nt * 8; idx += 256) {   // out[n][c]=sum_d PT[d][c]V[n][d]
        const int n = idx >> 3, cq = (idx & 7) << 2;
        const float* Vrow = &KVf[(long)(rb + n) * 512 + 256 + qc];
        f4_t o = (f4_t){0.f, 0.f, 0.f, 0.f};
        #pragma unroll
        for (int d4 = 0; d4 < 8; ++d4) {
            const f4_t vv = *(const f4_t*)&Vrow[d4 * 4];
            #pragma unroll
            for (int u = 0; u < 4; ++u)
                o += *(const f4_t*)&PT[(d4 * 4 + u) * 36 + cq] * vv[u];
        }
        us4_t h4, l4;
        #pragma unroll
        for (int q = 0; q < 4; ++q) { u16 h, l; bsplit(o[q], h, l); h4[q] = h; l4[q] = l; }
        const long oadr = (long)(rb + n) * 256 + qc + cq;
        *(us4_t*)&AOh[oadr] = h4;
        *(us4_t*)&AOl[oadr] = l4;
    }
}

// ---- row LayerNorm over 512 channels (token-major input, channel-major output) ----
__global__ __launch_bounds__(256)
void ln_tm(const float* __restrict__ PREf, const float* __restrict__ gamma,
           const float* __restrict__ beta, float* __restrict__ out)
{
    __shared__ float tile[64 * 65];
    __shared__ float sb[64 * 4], s2b[64 * 4];
    __shared__ float muS[64], rsS[64];
    const int r0 = blockIdx.x << 6;
    const int b = r0 / NTOK, n0 = r0 % NTOK;
    const int t = threadIdx.x;
    {
        const int tok = t >> 2, qq = t & 3;
        const float* row = PREf + (long)(r0 + tok) * 512 + qq * 128;
        float s = 0.f, s2 = 0.f;
        #pragma unroll 8
        for (int i = 0; i < 32; ++i) {
            const f4_t v4 = *(const f4_t*)&row[i * 4];
            s += v4[0] + v4[1] + v4[2] + v4[3];
            s2 = fmaf(v4[0], v4[0], s2); s2 = fmaf(v4[1], v4[1], s2);
            s2 = fmaf(v4[2], v4[2], s2); s2 = fmaf(v4[3], v4[3], s2);
        }
        sb[tok * 4 + qq] = s; s2b[tok * 4 + qq] = s2;
    }
    __syncthreads();
    if (t < 64) {
        const float s  = sb[t * 4] + sb[t * 4 + 1] + sb[t * 4 + 2] + sb[t * 4 + 3];
        const float s2 = s2b[t * 4] + s2b[t * 4 + 1] + s2b[t * 4 + 2] + s2b[t * 4 + 3];
        const float mu = s * (1.f / 512.f);
        const float var = s2 * (1.f / 512.f) - mu * mu;
        muS[t] = mu;
        rsS[t] = 1.f / sqrtf(var + 1e-5f);
    }
    __syncthreads();
    const int cc = t & 63, tq = t >> 6;
    for (int ct = 0; ct < 8; ++ct) {
        const float ga = gamma[ct * 64 + cc], be = beta[ct * 64 + cc];
        #pragma unroll
        for (int i = 0; i < 16; ++i) {
            const int tok = tq * 16 + i;
            const float v = PREf[(long)(r0 + tok) * 512 + ct * 64 + cc];
            tile[cc * 65 + tok] = (v - muS[tok]) * rsS[tok] * ga + be;
        }
        __syncthreads();
        #pragma unroll
        for (int i = 0; i < 16; ++i) {
            const int ccr = tq * 16 + i;
            out[(long)b * DIMC * NTOK + (long)(ct * 64 + ccr) * NTOK + n0 + cc] = tile[ccr * 65 + cc];
        }
        __syncthreads();
    }
}

extern "C" void kernel_launch(void* const* d_in, const int* in_sizes, int n_in,
                              void* d_out, int out_size, void* d_ws, size_t ws_size,
                              hipStream_t stream)
{
    const float* x1     = (const float*)d_in[0];
    const float* x2     = (const float*)d_in[1];
    const float* W_lin  = (const float*)d_in[2];
    const float* b_lin  = (const float*)d_in[3];
    const float* W_down = (const float*)d_in[4];
    const float* b_down = (const float*)d_in[5];
    const float* W_up   = (const float*)d_in[6];
    const float* b_up   = (const float*)d_in[7];
    const float* Wq     = (const float*)d_in[8];
    const float* Wk     = (const float*)d_in[9];
    const float* Wv     = (const float*)d_in[10];
    const float* Wo     = (const float*)d_in[11];
    const float* temp   = (const float*)d_in[12];
    const float* W_end  = (const float*)d_in[13];
    const float* b_end  = (const float*)d_in[14];
    const float* gamma  = (const float*)d_in[15];
    const float* beta   = (const float*)d_in[16];

    const size_t MB = 1ull << 20;
    char* base = (char*)d_ws;
    // persistent slots
    u16* X1h = (u16*)(base + 0 * MB);          // 20MB each plane
    u16* X1l = (u16*)(base + 20 * MB);
    u16* X2h = (u16*)(base + 40 * MB);
    u16* X2l = (u16*)(base + 60 * MB);
    u16* Wph = (u16*)(base + 80 * MB);         // 2.5MB each
    u16* Wpl = (u16*)(base + 80 * MB + 2621440);
    u16* Y1h = (u16*)(base + 85 * MB);         // [R][512] planes, 20MB each
    u16* Y1l = (u16*)(base + 105 * MB);
    u16* U1h = (u16*)(base + 125 * MB);
    u16* U1l = (u16*)(base + 145 * MB);
    u16* U2h = (u16*)(base + 165 * MB);
    u16* U2l = (u16*)(base + 185 * MB);
    u16* XBh = (u16*)(base + 205 * MB);        // [R][256] planes, 10MB each
    u16* XBl = (u16*)(base + 215 * MB);
    // aliases (lifetime-checked)
    float* Qf  = (float*)(base + 0 * MB);      // over X1 (dead after y1/u1)
    u16* AOh   = (u16*)(base + 20 * MB);
    u16* AOl   = (u16*)(base + 30 * MB);
    u16* OCh   = (u16*)(base + 0 * MB);        // over Qf (dead after attn)
    u16* OCl   = (u16*)(base + 10 * MB);
    u16* YBh   = (u16*)(base + 40 * MB);       // over X2h (dead after u2)
    u16* YBl   = (u16*)(base + 50 * MB);
    float* KVf = (float*)(base + 40 * MB);     // over YB (dead after q) + X2l
    float* PREf= (float*)(base + 40 * MB);     // over KVf (dead after attn)
    u16* Yh    = (u16*)(base + 165 * MB);      // over U2 (dead after yb)
    u16* Yl    = (u16*)(base + 185 * MB);

    // weight plane offsets (elements)
    const long WL = 0, WD = 524288, WU = 655360, WE = 786432,
               WQ = 1048576, WKV = 1114112, WO = 1245184;

    const dim3 blk(256);

    pack_x_k<<<dim3(8, 5, 128), blk, 0, stream>>>(x1, x2, X1h, X1l, X2h, X2l);
    pack_w_k<<<dim3(5120), blk, 0, stream>>>(W_lin, W_down, W_up, W_end, Wq, Wk, Wv, Wo, Wph, Wpl);

    // y1 = relu(t1@W_lin[:, :512] + b)         -> Y1 packed
    gemm_tm<F_BIAS | F_RELU | F_PACK, 512, 4><<<dim3(640), blk, 0, stream>>>(
        Wph + WL, Wpl + WL, X1h, X1l,
        nullptr, 0, Y1h, Y1l, 512, b_lin,
        nullptr, nullptr, 0, nullptr, nullptr, 0, nullptr);
    // u1 = relu(t1@W_lin[:, 512:] + b[512:])   -> U1 packed
    gemm_tm<F_BIAS | F_RELU | F_PACK, 512, 4><<<dim3(640), blk, 0, stream>>>(
        Wph + WL + 512 * 512, Wpl + WL + 512 * 512, X1h, X1l,
        nullptr, 0, U1h, U1l, 512, b_lin + 512,
        nullptr, nullptr, 0, nullptr, nullptr, 0, nullptr);
    // u2 = relu(t2@W_lin[:, 512:] + b[512:])   -> U2 packed
    gemm_tm<F_BIAS | F_RELU | F_PACK, 512, 4><<<dim3(640), blk, 0, stream>>>(
        Wph + WL + 512 * 512, Wpl + WL + 512 * 512, X2h, X2l,
        nullptr, 0, U2h, U2l, 512, b_lin + 512,
        nullptr, nullptr, 0, nullptr, nullptr, 0, nullptr);
    // xb = relu(u1@W_down + b_down)            -> XB packed
    gemm_tm<F_BIAS | F_RELU | F_PACK, 512, 2><<<dim3(320), blk, 0, stream>>>(
        Wph + WD, Wpl + WD, U1h, U1l,
        nullptr, 0, XBh, XBl, 256, b_down,
        nullptr, nullptr, 0, nullptr, nullptr, 0, nullptr);
    // yb = relu(u2@W_down + b_down)            -> YB packed
    gemm_tm<F_BIAS | F_RELU | F_PACK, 512, 2><<<dim3(320), blk, 0, stream>>>(
        Wph + WD, Wpl + WD, U2h, U2l,
        nullptr, 0, YBh, YBl, 256, b_down,
        nullptr, nullptr, 0, nullptr, nullptr, 0, nullptr);
    // q = yb@Wq^T                              -> Qf fp32
    gemm_tm<F_F32, 256, 2><<<dim3(320), blk, 0, stream>>>(
        Wph + WQ, Wpl + WQ, YBh, YBl,
        Qf, 256, nullptr, nullptr, 0, nullptr,
        nullptr, nullptr, 0, nullptr, nullptr, 0, nullptr);
    // k|v = xb@[Wk;Wv]^T                       -> KVf fp32 [r][512]
    gemm_tm<F_F32, 256, 4><<<dim3(640), blk, 0, stream>>>(
        Wph + WKV, Wpl + WKV, XBh, XBl,
        KVf, 512, nullptr, nullptr, 0, nullptr,
        nullptr, nullptr, 0, nullptr, nullptr, 0, nullptr);
    // channel attention                         -> AO packed
    attn_tm<<<dim3(2, NHEAD, BB), blk, 0, stream>>>(Qf, KVf, AOh, AOl, temp);
    // outc = ao@Wo^T + xb                      -> OC packed
    gemm_tm<F_PACK | F_RES1P, 256, 2><<<dim3(320), blk, 0, stream>>>(
        Wph + WO, Wpl + WO, AOh, AOl,
        nullptr, 0, OCh, OCl, 256, nullptr,
        XBh, XBl, 256, nullptr, nullptr, 0, nullptr);
    // y = outc@W_up^T + b_up + y1 + u1         -> Y packed
    gemm_tm<F_BIAS | F_PACK | F_RES1P | F_RES2P, 256, 4><<<dim3(640), blk, 0, stream>>>(
        Wph + WU, Wpl + WU, OCh, OCl,
        nullptr, 0, Yh, Yl, 512, b_up,
        Y1h, Y1l, 512, U1h, U1l, 512, nullptr);
    // pre = y@W_end^T + b_end + t1             -> PREf fp32
    gemm_tm<F_BIAS | F_F32 | F_RESX1, 512, 4><<<dim3(640), blk, 0, stream>>>(
        Wph + WE, Wpl + WE, Yh, Yl,
        PREf, 512, nullptr, nullptr, 0, b_end,
        nullptr, nullptr, 0, nullptr, nullptr, 0, x1);
    // LayerNorm + transpose back to (B,512,16,20)
    ln_tm<<<dim3(320), blk, 0, stream>>>(PREf, gamma, beta, (float*)d_out);
}

// Round 10
// 637.970 us; speedup vs baseline: 1.5043x; 1.5043x over previous
//
#include <hip/hip_runtime.h>
#include <math.h>

#define NTOK 320
#define BB   64
#define RTOT (BB * NTOK)   // 20480 token rows
#define DIMC 512
#define HIDC 256
#define NHEAD 8

typedef unsigned short u16;
typedef __attribute__((ext_vector_type(8))) short bf8_t;           // 8 bf16
typedef __attribute__((ext_vector_type(4))) float f4_t;
typedef __attribute__((ext_vector_type(4))) unsigned short us4_t;

#define F_BIAS  1
#define F_RELU  2
#define F_F32   4
#define F_PACK  8
#define F_RES1P 16
#define F_RES2P 32
#define F_RESX1 64

__device__ __forceinline__ void bsplit(float f, u16& h, u16& l) {
    const unsigned u = __float_as_uint(f);
    h = (u16)(u >> 16);
    const float fl = f - __uint_as_float(u & 0xffff0000u);
    l = (u16)(__float_as_uint(fl) >> 16);
}
__device__ __forceinline__ float brecon(u16 h, u16 l) {
    return __uint_as_float((unsigned)h << 16) + __uint_as_float((unsigned)l << 16);
}

// async global->LDS, 16B per lane; LDS dest is wave-uniform base + lane*16
__device__ __forceinline__ void gl_lds16(const u16* g, u16* l) {
    __builtin_amdgcn_global_load_lds(
        (const __attribute__((address_space(1))) unsigned int*)(const void*)g,
        (__attribute__((address_space(3))) unsigned int*)(void*)l,
        16, 0, 0);
}

// ---- pack all weights into bf16 hi/lo planes, orientation [out_j][d] ----
// offsets (elements): WL=0[1024][512] WD=524288[256][512] WU=655360[512][256]
// WE=786432[512][512] WQ=1048576[256][256] WKV=1114112[2x256][256] WO=1245184[256][256]
__global__ __launch_bounds__(256)
void pack_w_k(const float* __restrict__ Wlin, const float* __restrict__ Wdown,
              const float* __restrict__ Wup,  const float* __restrict__ Wend,
              const float* __restrict__ Wq,   const float* __restrict__ Wk,
              const float* __restrict__ Wv,   const float* __restrict__ Wo,
              u16* __restrict__ Ph, u16* __restrict__ Pl)
{
    const int idx = blockIdx.x * 256 + threadIdx.x;
    if (idx >= 1310720) return;
    float v;
    int i = idx;
    if      (i < 524288) { const int j = i >> 9, d = i & 511; v = Wlin[d * 1024 + j]; }
    else if (i < 655360) { i -= 524288; const int j = i >> 9, d = i & 511; v = Wdown[d * 256 + j]; }
    else if (i < 786432) { i -= 655360; const int j = i >> 8, d = i & 255; v = Wup[d * 512 + j]; }
    else if (i < 1048576){ i -= 786432; const int j = i >> 9, d = i & 511; v = Wend[d * 512 + j]; }
    else if (i < 1114112){ v = Wq[i - 1048576]; }
    else if (i < 1245184){ i -= 1114112; v = (i < 65536) ? Wk[i] : Wv[i - 65536]; }
    else                 { v = Wo[i - 1245184]; }
    u16 h, l; bsplit(v, h, l);
    Ph[idx] = h; Pl[idx] = l;
}

// ---- transpose x (B,512,320) channel-major -> token-major packed planes ----
__global__ __launch_bounds__(256)
void pack_x_k(const float* __restrict__ x1, const float* __restrict__ x2,
              u16* __restrict__ X1h, u16* __restrict__ X1l,
              u16* __restrict__ X2h, u16* __restrict__ X2l)
{
    __shared__ float tile[64 * 65];
    const int b = blockIdx.z & 63, which = blockIdx.z >> 6;
    const float* src = which ? x2 : x1;
    u16* Dh = which ? X2h : X1h;
    u16* Dl = which ? X2l : X1l;
    const int c0 = blockIdx.x << 6, n0 = blockIdx.y << 6;
    const int t = threadIdx.x, col = t & 63, rq = t >> 6;
    const float* sb_ = src + (long)b * DIMC * NTOK;
    #pragma unroll
    for (int i = 0; i < 16; ++i) {
        const int c = rq * 16 + i;
        tile[c * 65 + col] = sb_[(long)(c0 + c) * NTOK + n0 + col];
    }
    __syncthreads();
    #pragma unroll
    for (int i = 0; i < 16; ++i) {
        const int nr = rq * 16 + i;
        u16 h, l; bsplit(tile[col * 65 + nr], h, l);
        const long o = (long)(b * NTOK + n0 + nr) * DIMC + c0 + col;
        Dh[o] = h; Dl[o] = l;
    }
}

// ---- m97-style bf16x3 MFMA GEMM: global_load_lds staging + linear LDS ----
// C[r][j] = epi( sum_d B[r][d] * A[j][d] ); A,B packed bf16 hi/lo planes.
// Block 128(j) x 128(r), BK=32, 4 waves 2x2 (wave tile 64x64), LDS 32KB.
// Per slab: 32 wave-issues of global_load_lds (1KB), 16 ds_read_b128/wave, 48 MFMA/wave.
template<int FLAGS, int DK, int JB>
__global__ __launch_bounds__(256)
void gemm_lds(const u16* __restrict__ Agh, const u16* __restrict__ Agl,
              const u16* __restrict__ Bgh, const u16* __restrict__ Bgl, int ldb,
              float* __restrict__ Cf, int ldcf,
              u16* __restrict__ Ch, u16* __restrict__ Cl, int ldcp,
              const float* __restrict__ bias,
              const u16* __restrict__ R1h, const u16* __restrict__ R1l, int ldr1,
              const u16* __restrict__ R2h, const u16* __restrict__ R2l, int ldr2,
              const float* __restrict__ xres)
{
    __shared__ u16 Ah[128 * 32], Al[128 * 32], Bh[128 * 32], Bl[128 * 32]; // 8KB each

    // XCD-chunked bijective swizzle (grid = JB*160, divisible by 8)
    const int nwg = JB * 160;
    const int nb  = (blockIdx.x & 7) * (nwg >> 3) + (blockIdx.x >> 3);
    const int j0 = (nb % JB) * 128;
    const int r0 = (nb / JB) * 128;

    const int t = threadIdx.x, lane = t & 63, wv = t >> 6;
    const int wq = wv >> 1, wr = wv & 1;
    const int r16 = lane & 15, g = lane >> 4;

    // staging role: wave 0->Ah, 1->Al, 2->Bh, 3->Bl; 8 issues x 1KB each
    u16* dst = (wv == 0) ? Ah : (wv == 1) ? Al : (wv == 2) ? Bh : Bl;
    const u16* src = (wv == 0) ? Agh : (wv == 1) ? Agl : (wv == 2) ? Bgh : Bgl;
    const int  lrow = lane >> 2, lchunk = lane & 3;
    const long rowstride = (wv < 2) ? (long)DK : (long)ldb;
    const long sbase = (wv < 2)
        ? (long)(j0 + lrow) * DK + lchunk * 8
        : (long)(r0 + lrow) * ldb + lchunk * 8;

    f4_t acc[4][4];
    #pragma unroll
    for (int i = 0; i < 4; ++i)
        #pragma unroll
        for (int j = 0; j < 4; ++j)
            acc[i][j] = (f4_t){0.f, 0.f, 0.f, 0.f};

    for (int d0 = 0; d0 < DK; d0 += 32) {
        #pragma unroll
        for (int i = 0; i < 8; ++i)
            gl_lds16(src + sbase + (long)i * 16 * rowstride + d0, dst + i * 512);
        __syncthreads();   // drains vmcnt before barrier (compiler-enforced)

        bf8_t ah[4], al[4], bh[4], bl[4];
        #pragma unroll
        for (int fm = 0; fm < 4; ++fm) {
            const int o = (wq * 64 + fm * 16 + r16) * 32 + g * 8;
            ah[fm] = *(const bf8_t*)&Ah[o];
            al[fm] = *(const bf8_t*)&Al[o];
        }
        #pragma unroll
        for (int fn = 0; fn < 4; ++fn) {
            const int o = (wr * 64 + fn * 16 + r16) * 32 + g * 8;
            bh[fn] = *(const bf8_t*)&Bh[o];
            bl[fn] = *(const bf8_t*)&Bl[o];
        }
        #pragma unroll
        for (int fm = 0; fm < 4; ++fm)
            #pragma unroll
            for (int fn = 0; fn < 4; ++fn) {
                acc[fm][fn] = __builtin_amdgcn_mfma_f32_16x16x32_bf16(ah[fm], bh[fn], acc[fm][fn], 0, 0, 0);
                acc[fm][fn] = __builtin_amdgcn_mfma_f32_16x16x32_bf16(ah[fm], bl[fn], acc[fm][fn], 0, 0, 0);
                acc[fm][fn] = __builtin_amdgcn_mfma_f32_16x16x32_bf16(al[fm], bh[fn], acc[fm][fn], 0, 0, 0);
            }
        __syncthreads();
    }

    // epilogue: frag D col = token (lane&15), rows = 4 consecutive j (g*4+reg)
    #pragma unroll
    for (int fm = 0; fm < 4; ++fm) {
        const int jb = j0 + wq * 64 + fm * 16 + g * 4;
        f4_t bv = (f4_t){0.f, 0.f, 0.f, 0.f};
        if (FLAGS & F_BIAS) bv = *(const f4_t*)&bias[jb];
        #pragma unroll
        for (int fn = 0; fn < 4; ++fn) {
            const int r = r0 + wr * 64 + fn * 16 + r16;
            f4_t v = acc[fm][fn];
            if (FLAGS & F_BIAS) v += bv;
            if (FLAGS & F_RES1P) {
                const us4_t rh = *(const us4_t*)&R1h[(long)r * ldr1 + jb];
                const us4_t rl = *(const us4_t*)&R1l[(long)r * ldr1 + jb];
                #pragma unroll
                for (int q = 0; q < 4; ++q) v[q] += brecon(rh[q], rl[q]);
            }
            if (FLAGS & F_RES2P) {
                const us4_t rh = *(const us4_t*)&R2h[(long)r * ldr2 + jb];
                const us4_t rl = *(const us4_t*)&R2l[(long)r * ldr2 + jb];
                #pragma unroll
                for (int q = 0; q < 4; ++q) v[q] += brecon(rh[q], rl[q]);
            }
            if (FLAGS & F_RESX1) {
                const unsigned rr = (unsigned)r;
                const int bb = rr / 320u;
                const int nn = rr - bb * 320u;
                #pragma unroll
                for (int q = 0; q < 4; ++q)
                    v[q] += xres[(long)bb * DIMC * NTOK + (long)(jb + q) * NTOK + nn];
            }
            if (FLAGS & F_RELU) {
                #pragma unroll
                for (int q = 0; q < 4; ++q) v[q] = fmaxf(v[q], 0.f);
            }
            if (FLAGS & F_F32)
                *(f4_t*)&Cf[(long)r * ldcf + jb] = v;
            if (FLAGS & F_PACK) {
                us4_t h4, l4;
                #pragma unroll
                for (int q = 0; q < 4; ++q) { u16 h, l; bsplit(v[q], h, l); h4[q] = h; l4[q] = l; }
                *(us4_t*)&Ch[(long)r * ldcp + jb] = h4;
                *(us4_t*)&Cl[(long)r * ldcp + jb] = l4;
            }
        }
    }
}

// ---- channel attention, token-major. grid (2 slices, 8 heads, 64 b). ----
// Q,K,V fp32 [r][256]. Q and K staged in LDS; V streamed from L2.
__global__ __launch_bounds__(256)
void attn_tm(const float* __restrict__ Qf, const float* __restrict__ Kf,
             const float* __restrict__ Vf,
             u16* __restrict__ AOh, u16* __restrict__ AOl,
             const float* __restrict__ temp)
{
    const int slice = blockIdx.x, h = blockIdx.y, b = blockIdx.z;
    const int rb = b * NTOK + (slice ? 64 : 0);
    const int Nt = slice ? 256 : 64;
    const int qc = h * 32;

    __shared__ float qs[256 * 34], ks[256 * 34];
    __shared__ float PT[32 * 36];                // P transposed: PT[d][c]
    __shared__ float invq[32], invk[32];
    const int t = threadIdx.x;

    for (int q = t; q < Nt * 8; q += 256) {      // stage Q,K (row=token, 32 ch)
        const int n = q >> 3, c4 = (q & 7) << 2;
        *(f4_t*)&qs[n * 34 + c4] = *(const f4_t*)&Qf[(long)(rb + n) * 256 + qc + c4];
        *(f4_t*)&ks[n * 34 + c4] = *(const f4_t*)&Kf[(long)(rb + n) * 256 + qc + c4];
    }
    __syncthreads();

    {   // l2 norms over tokens per channel
        const int c = t >> 3, l8 = t & 7;
        float sq = 0.f, sk = 0.f;
        for (int n = l8; n < Nt; n += 8) {
            const float qv = qs[n * 34 + c];
            sq = fmaf(qv, qv, sq);
            const float kv = ks[n * 34 + c];
            sk = fmaf(kv, kv, sk);
        }
        sq += __shfl_xor(sq, 1); sq += __shfl_xor(sq, 2); sq += __shfl_xor(sq, 4);
        sk += __shfl_xor(sk, 1); sk += __shfl_xor(sk, 2); sk += __shfl_xor(sk, 4);
        if (l8 == 0) {
            invq[c] = 1.f / fmaxf(sqrtf(sq), 1e-12f);
            invk[c] = 1.f / fmaxf(sqrtf(sk), 1e-12f);
        }
    }
    __syncthreads();

    {   // logits over d, softmax per row c  (all operands in LDS)
        const int c = t >> 3, db = (t & 7) << 2;
        float s0 = 0.f, s1 = 0.f, s2 = 0.f, s3 = 0.f;
        for (int n = 0; n < Nt; ++n) {
            const float qv = qs[n * 34 + c];
            const int o = n * 34 + db;
            s0 = fmaf(qv, ks[o + 0], s0);
            s1 = fmaf(qv, ks[o + 1], s1);
            s2 = fmaf(qv, ks[o + 2], s2);
            s3 = fmaf(qv, ks[o + 3], s3);
        }
        const float sc = invq[c] * temp[h];
        const float l0 = s0 * sc * invk[db + 0];
        const float l1 = s1 * sc * invk[db + 1];
        const float l2 = s2 * sc * invk[db + 2];
        const float l3 = s3 * sc * invk[db + 3];
        float m = fmaxf(fmaxf(l0, l1), fmaxf(l2, l3));
        m = fmaxf(m, __shfl_xor(m, 1));
        m = fmaxf(m, __shfl_xor(m, 2));
        m = fmaxf(m, __shfl_xor(m, 4));
        const float e0 = expf(l0 - m), e1 = expf(l1 - m);
        const float e2 = expf(l2 - m), e3 = expf(l3 - m);
        float s = e0 + e1 + e2 + e3;
        s += __shfl_xor(s, 1); s += __shfl_xor(s, 2); s += __shfl_xor(s, 4);
        const float inv = 1.f / s;
        PT[(db + 0) * 36 + c] = e0 * inv;
        PT[(db + 1) * 36 + c] = e1 * inv;
        PT[(db + 2) * 36 + c] = e2 * inv;
        PT[(db + 3) * 36 + c] = e3 * inv;
    }
    __syncthreads();

    for (int idx = t; idx < Nt * 8; idx += 256) {   // out[n][c]=sum_d PT[d][c]V[n][d]
        const int n = idx >> 3, cq = (idx & 7) << 2;
        const float* Vrow = &Vf[(long)(rb + n) * 256 + qc];
        f4_t o = (f4_t){0.f, 0.f, 0.f, 0.f};
        #pragma unroll
        for (int d4 = 0; d4 < 8; ++d4) {
            const f4_t vv = *(const f4_t*)&Vrow[d4 * 4];
            #pragma unroll
            for (int u = 0; u < 4; ++u)
                o += *(const f4_t*)&PT[(d4 * 4 + u) * 36 + cq] * vv[u];
        }
        us4_t h4, l4;
        #pragma unroll
        for (int q = 0; q < 4; ++q) { u16 h, l; bsplit(o[q], h, l); h4[q] = h; l4[q] = l; }
        const long oadr = (long)(rb + n) * 256 + qc + cq;
        *(us4_t*)&AOh[oadr] = h4;
        *(us4_t*)&AOl[oadr] = l4;
    }
}

// ---- row LayerNorm over 512 channels (token-major input, channel-major output) ----
__global__ __launch_bounds__(256)
void ln_tm(const float* __restrict__ PREf, const float* __restrict__ gamma,
           const float* __restrict__ beta, float* __restrict__ out)
{
    __shared__ float tile[64 * 65];
    __shared__ float sb[64 * 4], s2b[64 * 4];
    __shared__ float muS[64], rsS[64];
    const int r0 = blockIdx.x << 6;
    const int b = r0 / NTOK, n0 = r0 % NTOK;
    const int t = threadIdx.x;
    {
        const int tok = t >> 2, qq = t & 3;
        const float* row = PREf + (long)(r0 + tok) * 512 + qq * 128;
        float s = 0.f, s2 = 0.f;
        #pragma unroll 8
        for (int i = 0; i < 32; ++i) {
            const f4_t v4 = *(const f4_t*)&row[i * 4];
            s += v4[0] + v4[1] + v4[2] + v4[3];
            s2 = fmaf(v4[0], v4[0], s2); s2 = fmaf(v4[1], v4[1], s2);
            s2 = fmaf(v4[2], v4[2], s2); s2 = fmaf(v4[3], v4[3], s2);
        }
        sb[tok * 4 + qq] = s; s2b[tok * 4 + qq] = s2;
    }
    __syncthreads();
    if (t < 64) {
        const float s  = sb[t * 4] + sb[t * 4 + 1] + sb[t * 4 + 2] + sb[t * 4 + 3];
        const float s2 = s2b[t * 4] + s2b[t * 4 + 1] + s2b[t * 4 + 2] + s2b[t * 4 + 3];
        const float mu = s * (1.f / 512.f);
        const float var = s2 * (1.f / 512.f) - mu * mu;
        muS[t] = mu;
        rsS[t] = 1.f / sqrtf(var + 1e-5f);
    }
    __syncthreads();
    const int cc = t & 63, tq = t >> 6;
    for (int ct = 0; ct < 8; ++ct) {
        const float ga = gamma[ct * 64 + cc], be = beta[ct * 64 + cc];
        #pragma unroll
        for (int i = 0; i < 16; ++i) {
            const int tok = tq * 16 + i;
            const float v = PREf[(long)(r0 + tok) * 512 + ct * 64 + cc];
            tile[cc * 65 + tok] = (v - muS[tok]) * rsS[tok] * ga + be;
        }
        __syncthreads();
        #pragma unroll
        for (int i = 0; i < 16; ++i) {
            const int ccr = tq * 16 + i;
            out[(long)b * DIMC * NTOK + (long)(ct * 64 + ccr) * NTOK + n0 + cc] = tile[ccr * 65 + cc];
        }
        __syncthreads();
    }
}

extern "C" void kernel_launch(void* const* d_in, const int* in_sizes, int n_in,
                              void* d_out, int out_size, void* d_ws, size_t ws_size,
                              hipStream_t stream)
{
    const float* x1     = (const float*)d_in[0];
    const float* x2     = (const float*)d_in[1];
    const float* W_lin  = (const float*)d_in[2];
    const float* b_lin  = (const float*)d_in[3];
    const float* W_down = (const float*)d_in[4];
    const float* b_down = (const float*)d_in[5];
    const float* W_up   = (const float*)d_in[6];
    const float* b_up   = (const float*)d_in[7];
    const float* Wq     = (const float*)d_in[8];
    const float* Wk     = (const float*)d_in[9];
    const float* Wv     = (const float*)d_in[10];
    const float* Wo     = (const float*)d_in[11];
    const float* temp   = (const float*)d_in[12];
    const float* W_end  = (const float*)d_in[13];
    const float* b_end  = (const float*)d_in[14];
    const float* gamma  = (const float*)d_in[15];
    const float* beta   = (const float*)d_in[16];

    const size_t MB = 1ull << 20;
    char* base = (char*)d_ws;
    // persistent (lifetimes annotated); high-water 225MB
    u16* X1h = (u16*)(base + 0 * MB);          // dead after H1
    u16* X1l = (u16*)(base + 20 * MB);
    u16* X2h = (u16*)(base + 40 * MB);         // dead after U2
    u16* X2l = (u16*)(base + 60 * MB);
    u16* Wph = (u16*)(base + 80 * MB);
    u16* Wpl = (u16*)(base + 80 * MB + 2621440);
    u16* H1h = (u16*)(base + 85 * MB);         // [R][1024] = y1|u1, live till Y
    u16* H1l = (u16*)(base + 125 * MB);
    u16* U2h = (u16*)(base + 165 * MB);        // dead after YB
    u16* U2l = (u16*)(base + 185 * MB);
    u16* XBh = (u16*)(base + 205 * MB);        // live till OC
    u16* XBl = (u16*)(base + 215 * MB);
    // aliases
    u16* YBh   = (u16*)(base + 0 * MB);        // over X1h; dead after Q
    u16* YBl   = (u16*)(base + 10 * MB);
    float* Qf  = (float*)(base + 20 * MB);     // over X1l; dead after attn
    float* Kf  = (float*)(base + 0 * MB);      // over YB; dead after attn
    float* Vf  = (float*)(base + 60 * MB);     // over X2l; dead after attn
    u16* AOh   = (u16*)(base + 40 * MB);       // over X2h; dead after OC
    u16* AOl   = (u16*)(base + 50 * MB);
    u16* OCh   = (u16*)(base + 60 * MB);       // over Vf; dead after Y
    u16* OCl   = (u16*)(base + 70 * MB);
    u16* Yh    = (u16*)(base + 165 * MB);      // over U2; dead after PRE
    u16* Yl    = (u16*)(base + 185 * MB);
    float* PREf= (float*)(base + 0 * MB);      // over Kf/Qf; dead after LN

    const long WL = 0, WD = 524288, WU = 655360, WE = 786432,
               WQ = 1048576, WKV = 1114112, WO = 1245184;

    const dim3 blk(256);

    pack_x_k<<<dim3(8, 5, 128), blk, 0, stream>>>(x1, x2, X1h, X1l, X2h, X2l);
    pack_w_k<<<dim3(5120), blk, 0, stream>>>(W_lin, W_down, W_up, W_end, Wq, Wk, Wv, Wo, Wph, Wpl);

    // h1 = relu(t1@W_lin + b_lin)  (y1|u1 merged, J=1024) -> H1 packed
    gemm_lds<F_BIAS | F_RELU | F_PACK, 512, 8><<<dim3(1280), blk, 0, stream>>>(
        Wph + WL, Wpl + WL, X1h, X1l, 512,
        nullptr, 0, H1h, H1l, 1024, b_lin,
        nullptr, nullptr, 0, nullptr, nullptr, 0, nullptr);
    // u2 = relu(t2@W_lin[:,512:] + b[512:]) -> U2 packed
    gemm_lds<F_BIAS | F_RELU | F_PACK, 512, 4><<<dim3(640), blk, 0, stream>>>(
        Wph + WL + 512 * 512, Wpl + WL + 512 * 512, X2h, X2l, 512,
        nullptr, 0, U2h, U2l, 512, b_lin + 512,
        nullptr, nullptr, 0, nullptr, nullptr, 0, nullptr);
    // xb = relu(u1@W_down + b_down)  (u1 = H1 cols 512:, ldb 1024)
    gemm_lds<F_BIAS | F_RELU | F_PACK, 512, 2><<<dim3(320), blk, 0, stream>>>(
        Wph + WD, Wpl + WD, H1h + 512, H1l + 512, 1024,
        nullptr, 0, XBh, XBl, 256, b_down,
        nullptr, nullptr, 0, nullptr, nullptr, 0, nullptr);
    // yb = relu(u2@W_down + b_down)
    gemm_lds<F_BIAS | F_RELU | F_PACK, 512, 2><<<dim3(320), blk, 0, stream>>>(
        Wph + WD, Wpl + WD, U2h, U2l, 512,
        nullptr, 0, YBh, YBl, 256, b_down,
        nullptr, nullptr, 0, nullptr, nullptr, 0, nullptr);
    // q = yb@Wq^T -> Qf fp32
    gemm_lds<F_F32, 256, 2><<<dim3(320), blk, 0, stream>>>(
        Wph + WQ, Wpl + WQ, YBh, YBl, 256,
        Qf, 256, nullptr, nullptr, 0, nullptr,
        nullptr, nullptr, 0, nullptr, nullptr, 0, nullptr);
    // k = xb@Wk^T -> Kf fp32
    gemm_lds<F_F32, 256, 2><<<dim3(320), blk, 0, stream>>>(
        Wph + WKV, Wpl + WKV, XBh, XBl, 256,
        Kf, 256, nullptr, nullptr, 0, nullptr,
        nullptr, nullptr, 0, nullptr, nullptr, 0, nullptr);
    // v = xb@Wv^T -> Vf fp32
    gemm_lds<F_F32, 256, 2><<<dim3(320), blk, 0, stream>>>(
        Wph + WKV + 65536, Wpl + WKV + 65536, XBh, XBl, 256,
        Vf, 256, nullptr, nullptr, 0, nullptr,
        nullptr, nullptr, 0, nullptr, nullptr, 0, nullptr);
    // channel attention -> AO packed
    attn_tm<<<dim3(2, NHEAD, BB), blk, 0, stream>>>(Qf, Kf, Vf, AOh, AOl, temp);
    // outc = ao@Wo^T + xb -> OC packed
    gemm_lds<F_PACK | F_RES1P, 256, 2><<<dim3(320), blk, 0, stream>>>(
        Wph + WO, Wpl + WO, AOh, AOl, 256,
        nullptr, 0, OCh, OCl, 256, nullptr,
        XBh, XBl, 256, nullptr, nullptr, 0, nullptr);
    // y = outc@W_up^T + b_up + y1 + u1 -> Y packed
    gemm_lds<F_BIAS | F_PACK | F_RES1P | F_RES2P, 256, 4><<<dim3(640), blk, 0, stream>>>(
        Wph + WU, Wpl + WU, OCh, OCl, 256,
        nullptr, 0, Yh, Yl, 512, b_up,
        H1h, H1l, 1024, H1h + 512, H1l + 512, 1024, nullptr);
    // pre = y@W_end^T + b_end + t1 -> PREf fp32
    gemm_lds<F_BIAS | F_F32 | F_RESX1, 512, 4><<<dim3(640), blk, 0, stream>>>(
        Wph + WE, Wpl + WE, Yh, Yl, 512,
        PREf, 512, nullptr, nullptr, 0, b_end,
        nullptr, nullptr, 0, nullptr, nullptr, 0, x1);
    // LayerNorm + transpose back to (B,512,16,20)
    ln_tm<<<dim3(320), blk, 0, stream>>>(PREf, gamma, beta, (float*)d_out);
}